// Round 11
// baseline (211.729 us; speedup 1.0000x reference)
//
#include <hip/hip_runtime.h>
#include <hip/hip_bf16.h>
#include <math.h>

#define B_ 2
#define N_ 2048
#define E_ 1024
#define H_ 8

typedef __attribute__((ext_vector_type(8))) short frag8;       // 8 bf16 (4 VGPRs)
typedef __attribute__((ext_vector_type(4))) float f32x4;
typedef __attribute__((ext_vector_type(16))) float f32x16;
typedef __attribute__((ext_vector_type(8))) unsigned short u16x8;

constexpr float LAM_INIT = 0.7836057665316245f; // 0.8 - 0.6*exp(-0.3*12)
constexpr float LOG2E = 1.4426950408889634f;
constexpr float EXP2_GUARD = -23.083120654f;    // -16 * log2(e)

static __device__ __forceinline__ float fast_exp2(float x) {
#if __has_builtin(__builtin_amdgcn_exp2f)
  return __builtin_amdgcn_exp2f(x);
#else
  return exp2f(x);
#endif
}

static __device__ __forceinline__ ushort f2bf(float f) {
  union { float f; unsigned u; } v; v.f = f;
  unsigned r = (v.u + 0x7FFFu + ((v.u >> 16) & 1u)) >> 16;
  return (ushort)r;
}

static __device__ __forceinline__ unsigned pkbf(float a, float b) {
  __hip_bfloat162 h = __float22bfloat162_rn(make_float2(a, b));
  return *(unsigned*)&h;
}

static __device__ __forceinline__ void async16(const void* g, void* l) {
  __builtin_amdgcn_global_load_lds((const __attribute__((address_space(1))) void*)g,
                                   (__attribute__((address_space(3))) void*)l, 16, 0, 0);
}

// Build the PV B-frag from 4 packed-bf16 dwords using v_permlane32_swap_b32
// (VALU pipe) instead of 2x __shfl_xor(32) (LDS pipe ds_bpermute) + 8 cndmask.
// permlane32_swap(a,b): r0 = {a.lo32, b.lo32}, r1 = {a.hi32, b.hi32}  (verified R1-R10)
static __device__ __forceinline__ frag8 mkfrag(unsigned p0, unsigned p1,
                                               unsigned p2, unsigned p3) {
  auto r02 = __builtin_amdgcn_permlane32_swap((int)p0, (int)p2, false, false);
  auto r13 = __builtin_amdgcn_permlane32_swap((int)p1, (int)p3, false, false);
  union { unsigned u[4]; frag8 f; } u;
  u.u[0] = (unsigned)r02[0];
  u.u[1] = (unsigned)r13[0];
  u.u[2] = (unsigned)r02[1];
  u.u[3] = (unsigned)r13[1];
  return u.f;
}

// ---------------- fused prep: cast x -> bf16 | 4x weight transpose+cast | lambda ----------------
__global__ __launch_bounds__(256) void prep_kernel(
    const float* __restrict__ x,
    const float* __restrict__ Wq, const float* __restrict__ Wk,
    const float* __restrict__ Wv, const float* __restrict__ Wo,
    const float* __restrict__ lq1, const float* __restrict__ lk1,
    const float* __restrict__ lq2, const float* __restrict__ lk2,
    ushort* __restrict__ xb, ushort* __restrict__ wqkvt, ushort* __restrict__ wot,
    float* __restrict__ lam_out) {
  __shared__ ushort t[64][72];
  const int bx = blockIdx.x;
  const int tid = threadIdx.x;
  if (bx < 2048) {
    // cast x (8 elems/thread)
    int i = bx * 256 + tid;
    const float4* sp = (const float4*)x + (size_t)i * 2;
    float4 a = sp[0], b = sp[1];
    u16x8 o;
    o[0] = f2bf(a.x); o[1] = f2bf(a.y); o[2] = f2bf(a.z); o[3] = f2bf(a.w);
    o[4] = f2bf(b.x); o[5] = f2bf(b.y); o[6] = f2bf(b.z); o[7] = f2bf(b.w);
    *(u16x8*)(xb + (size_t)i * 8) = o;
  } else if (bx < 3072) {
    int idx = bx - 2048;
    int sel = idx >> 8, rem = idx & 255;
    const float* W = (sel == 0) ? Wq : (sel == 1) ? Wk : (sel == 2) ? Wv : Wo;
    ushort* Wt = (sel < 3) ? (wqkvt + (size_t)sel * 1048576) : wot;
    const int c0 = (rem & 15) * 64, r0 = (rem >> 4) * 64;
    {
      int r = tid >> 2, cc = (tid & 3) * 16;
      const float* sp = W + (size_t)(r0 + r) * 1024 + c0 + cc;
      #pragma unroll
      for (int j = 0; j < 4; j++) {
        float4 a = *(const float4*)(sp + j * 4);
        t[cc + j * 4 + 0][r] = f2bf(a.x);
        t[cc + j * 4 + 1][r] = f2bf(a.y);
        t[cc + j * 4 + 2][r] = f2bf(a.z);
        t[cc + j * 4 + 3][r] = f2bf(a.w);
      }
    }
    __syncthreads();
    int c = tid >> 2, rr = (tid & 3) * 16;
    ushort* dp = Wt + (size_t)(c0 + c) * 1024 + r0 + rr;
    *(u16x8*)dp = *(u16x8*)&t[c][rr];
    *(u16x8*)(dp + 8) = *(u16x8*)&t[c][rr + 8];
  } else {
    if (tid < 64) {
      float t1 = lq1[tid] * lk1[tid];
      float t2 = lq2[tid] * lk2[tid];
      #pragma unroll
      for (int off = 32; off > 0; off >>= 1) {
        t1 += __shfl_down(t1, off);
        t2 += __shfl_down(t2, off);
      }
      if (tid == 0) lam_out[0] = expf(t1) - expf(t2) + LAM_INIT;
    }
  }
}

// ---------------- fused QK + V^T projection GEMM (768 blocks = 3/CU, XCD-chunked) --------------
// id < 512:  qkb[4096][2048]  = xb @ [Wq;Wk]^T   (q cols scaled by D^-0.5*log2e)
// id >= 512: vtb[1024][4096]  = Wv^T @ xb^T      (V produced already transposed)
// T1 XCD-chunk remap (R9/R10-verified): consecutive ids share the A-panel; chunked, each XCD
// gets 96 contiguous ids = ~6 A-panels (1.5MB, L2-resident, 16x reuse). 768 = 8*96 bijective.
// Inner loop = R4's proven 2-barrier BK=32 form (R7 dbuf regressed; R8 BK=64+swizzle null).
__global__ __launch_bounds__(256) void gemm_qkv(const ushort* __restrict__ xb,
                                                const ushort* __restrict__ wqkvt,
                                                ushort* __restrict__ qkb,
                                                ushort* __restrict__ vtb, float qscale) {
  __shared__ ushort As[4096]; // 128 rows x 32 (k-contig), 8 KB
  __shared__ ushort Bs[4096];
  const int id0 = blockIdx.x;
  const int id = (id0 & 7) * 96 + (id0 >> 3); // XCD-chunk remap (bijective, 768 = 8*96)
  const ushort* A; const ushort* Bt; ushort* C;
  int m0, n0, ldc;
  float sc;
  if (id < 512) {
    m0 = (id >> 4) * 128; n0 = (id & 15) * 128;
    A = xb; Bt = wqkvt; C = qkb; ldc = 2048;
    sc = (n0 < 1024) ? qscale : 1.0f;
  } else {
    int id2 = id - 512;
    m0 = (id2 & 7) * 128; n0 = (id2 >> 3) * 128;
    A = wqkvt + 2 * 1048576; Bt = xb; C = vtb; ldc = 4096;
    sc = 1.0f;
  }
  const int tid = threadIdx.x;
  const int w = tid >> 6, l = tid & 63;
  const int quad = l >> 4, col16 = l & 15;
  const int wm = (w & 1) * 64, wn = (w >> 1) * 64;
  const int lrow = l >> 2, lcol = (l & 3) * 8;

  f32x4 acc[4][4];
  #pragma unroll
  for (int mt = 0; mt < 4; mt++)
    #pragma unroll
    for (int nt = 0; nt < 4; nt++) acc[mt][nt] = (f32x4){0.f, 0.f, 0.f, 0.f};

  for (int k0 = 0; k0 < 1024; k0 += 32) {
    __syncthreads();
    #pragma unroll
    for (int i = 0; i < 4; i++) {
      int s = w * 4 + i; // wave-uniform
      if (s < 8) {
        const ushort* gp = A + (size_t)(m0 + s * 16 + lrow) * 1024 + k0 + lcol;
        async16(gp, (char*)As + s * 1024);
      } else {
        int s2 = s - 8;
        const ushort* gp = Bt + (size_t)(n0 + s2 * 16 + lrow) * 1024 + k0 + lcol;
        async16(gp, (char*)Bs + s2 * 1024);
      }
    }
    __syncthreads();
    frag8 af[4], bfr[4];
    #pragma unroll
    for (int mt = 0; mt < 4; mt++)
      af[mt] = *(const frag8*)((const char*)As + (wm + mt * 16 + col16) * 64 + quad * 16);
    #pragma unroll
    for (int nt = 0; nt < 4; nt++)
      bfr[nt] = *(const frag8*)((const char*)Bs + (wn + nt * 16 + col16) * 64 + quad * 16);
    #pragma unroll
    for (int mt = 0; mt < 4; mt++)
      #pragma unroll
      for (int nt = 0; nt < 4; nt++)
        acc[mt][nt] = __builtin_amdgcn_mfma_f32_16x16x32_bf16(af[mt], bfr[nt], acc[mt][nt], 0, 0, 0);
  }

  #pragma unroll
  for (int mt = 0; mt < 4; mt++)
    #pragma unroll
    for (int r = 0; r < 4; r++) {
      int m = m0 + wm + mt * 16 + quad * 4 + r;
      #pragma unroll
      for (int nt = 0; nt < 4; nt++) {
        int n = n0 + wn + nt * 16 + col16;
        C[(size_t)m * ldc + n] = f2bf(acc[mt][nt][r] * sc);
      }
    }
}

// ---------------- output projection GEMM, 64x128 tiles (512 blocks = 2/CU) ----------------
__global__ __launch_bounds__(256) void gemm_out(const ushort* __restrict__ A,
                                                const ushort* __restrict__ Bt,
                                                float* __restrict__ Cp) {
  __shared__ ushort As[2048]; // 64 rows x 32, 4 KB
  __shared__ ushort Bs[4096]; // 128 rows x 32, 8 KB
  const int tid = threadIdx.x;
  const int w = tid >> 6, l = tid & 63;
  const int quad = l >> 4, col16 = l & 15;
  const int m0 = blockIdx.y * 64, n0 = blockIdx.x * 128;
  const int wm = (w & 1) * 32, wn = (w >> 1) * 64;
  const int lrow = l >> 2, lcol = (l & 3) * 8;

  f32x4 acc[2][4];
  #pragma unroll
  for (int mt = 0; mt < 2; mt++)
    #pragma unroll
    for (int nt = 0; nt < 4; nt++) acc[mt][nt] = (f32x4){0.f, 0.f, 0.f, 0.f};

  for (int k0 = 0; k0 < 1024; k0 += 32) {
    __syncthreads();
    #pragma unroll
    for (int i = 0; i < 3; i++) {
      int s = w * 3 + i; // 0..11, wave-uniform
      if (s < 4) {
        const ushort* gp = A + (size_t)(m0 + s * 16 + lrow) * 1024 + k0 + lcol;
        async16(gp, (char*)As + s * 1024);
      } else {
        int s2 = s - 4;
        const ushort* gp = Bt + (size_t)(n0 + s2 * 16 + lrow) * 1024 + k0 + lcol;
        async16(gp, (char*)Bs + s2 * 1024);
      }
    }
    __syncthreads();
    frag8 af[2], bfr[4];
    #pragma unroll
    for (int mt = 0; mt < 2; mt++)
      af[mt] = *(const frag8*)((const char*)As + (wm + mt * 16 + col16) * 64 + quad * 16);
    #pragma unroll
    for (int nt = 0; nt < 4; nt++)
      bfr[nt] = *(const frag8*)((const char*)Bs + (wn + nt * 16 + col16) * 64 + quad * 16);
    #pragma unroll
    for (int mt = 0; mt < 2; mt++)
      #pragma unroll
      for (int nt = 0; nt < 4; nt++)
        acc[mt][nt] = __builtin_amdgcn_mfma_f32_16x16x32_bf16(af[mt], bfr[nt], acc[mt][nt], 0, 0, 0);
  }

  #pragma unroll
  for (int mt = 0; mt < 2; mt++)
    #pragma unroll
    for (int r = 0; r < 4; r++) {
      int m = m0 + wm + mt * 16 + quad * 4 + r;
      #pragma unroll
      for (int nt = 0; nt < 4; nt++) {
        int n = n0 + wn + nt * 16 + col16;
        Cp[(size_t)m * 1024 + n] = acc[mt][nt][r];
      }
    }
}

// ---------------- MFMA flash attention, paired half-heads, 2-TILE BARRIER PHASES ---------------
// R10 best config (256 blocks x 512 thr = 1/CU, R4 compute) with ONE schedule change:
// TWO tiles per barrier phase (4 buffers A0/A1/B0/B1). Halves barrier+vmcnt(0)-drain count
// (32 -> 16), doubles the prefetch batch (8 outstanding wave-loads) and the compute cover per
// load (~2 phases). Same math, same registers, same total LDS (131584: epi aliases A0/A1 —
// safe: last bufA read precedes the final sync of the loop).
// Rationale: flash is operand-BW bound (R5: moving V LDS->L1 was null — similar-BW pipes) with
// ~30% unexplained stall; the per-tile full drain stalling all 8 lockstep waves is the last
// untried schedule cost (m97 analysis: ~20% barrier-drain). Pre-registered null: dur >= 69us
// at unchanged VGPR/FETCH => structural ceiling of this design.
// Refuted levers: LDS traffic (R5), barrier grouping (R6), V placement (R3/R5), chain
// reordering (R9, compiler serialized), 2x q-rows (R1 spill).
__global__ __launch_bounds__(512, 2) void flash_kernel(const ushort* __restrict__ qk,
                                                       const ushort* __restrict__ vt,
                                                       const float* __restrict__ lam_p,
                                                       const float* __restrict__ ln_g,
                                                       const float* __restrict__ ln_b,
                                                       ushort* __restrict__ onorm) {
  // XCD-chunked remap: L = r + 8*s -> hb = r + 8*(s&1), qb = s>>1 (bijective).
  const int L = blockIdx.x;
  const int hb = (L & 7) | (((L >> 3) & 1) << 3); // 0..15
  const int qb = L >> 4;                          // 0..15
  const int h = hb & 7, b = hb >> 3;

  const int tid = threadIdx.x;
  const int w = tid >> 6;                 // 0..7
  const int hsel = w >> 2;                // 0: even half-head, 1: odd
  const int h2 = 2 * h + hsel;
  const int lane31 = tid & 31, half = (tid & 63) >> 5;
  const int qloc = (w & 3) * 32 + lane31; // q-row within block's 128
  const int i0 = qb * 128 + (w & 3) * 32; // wave's first q-row (global)

  __shared__ char smem[131584];
  char* A0 = smem;              // [K0 8K | K1 8K | V 16K] per tile slot
  char* A1 = smem + 32768;
  char* B0 = smem + 65536;
  char* B1 = smem + 98304;
  float* epi = (float*)smem;    // 64 KB O-exchange, aliases A0+A1 (used after final barrier)
  float* epi_l = (float*)(smem + 131072); // 128 floats

  const float lam = lam_p[0];

  // hoisted Q B-frags (per-wave, own half-head)
  frag8 qf[4];
  #pragma unroll
  for (int chk = 0; chk < 4; chk++) {
    const ushort* qp = qk + (size_t)(b * N_ + i0 + lane31) * 2048 +
                       h2 * 64 + chk * 16 + half * 8;
    qf[chk] = *(const frag8*)qp;
  }

  f32x16 o_[4];
  #pragma unroll
  for (int cm = 0; cm < 4; cm++)
    #pragma unroll
    for (int i = 0; i < 16; i++) o_[cm][i] = 0.f;
  float la0 = 0.f, la1 = 0.f;

  // stage one 64-k tile: K(2h) 8KB + K(2h+1) 8KB + V 16KB = 32KB, 4 async16/thread.
  // LDS dest linear (global source pre-swizzled) per rule #21.
  auto stage = [&](int k0, char* buf) {
    {
      int row = tid >> 3, sch = (tid & 7) ^ (row & 7);
      const ushort* kg = qk + (size_t)(b * N_ + k0 + row) * 2048 + 1024 + (2 * h) * 64 + sch * 8;
      async16(kg, buf + w * 1024);
    }
    {
      int row = tid >> 3, sch = (tid & 7) ^ (row & 7);
      const ushort* kg = qk + (size_t)(b * N_ + k0 + row) * 2048 + 1024 + (2 * h + 1) * 64 + sch * 8;
      async16(kg, buf + 8192 + w * 1024);
    }
    #pragma unroll
    for (int it = 0; it < 2; it++) {
      int j = it * 512 + tid;
      int row = j >> 3, sch = (j & 7) ^ (row & 7);
      const ushort* vg = vt + (size_t)(h * 128 + row) * 4096 + b * N_ + k0 + sch * 8;
      async16(vg, buf + 16384 + it * 8192 + w * 1024);
    }
  };

  auto compute = [&](const char* buf) {
    const char* Kb = buf + hsel * 8192;
    const char* Vb = buf + 16384;
    #pragma unroll
    for (int kh = 0; kh < 2; kh++) {
      f32x16 st;
      #pragma unroll
      for (int i = 0; i < 16; i++) st[i] = EXP2_GUARD;
      const int r = kh * 32 + lane31;
      __builtin_amdgcn_s_setprio(1);
      #pragma unroll
      for (int chk = 0; chk < 4; chk++) {
        frag8 a = *(const frag8*)(Kb + r * 128 + (((chk << 1) | half) ^ (r & 7)) * 16);
        st = __builtin_amdgcn_mfma_f32_32x32x16_bf16(a, qf[chk], st, 0, 0, 0);
      }
      __builtin_amdgcn_s_setprio(0);
      unsigned pk[8];
      #pragma unroll
      for (int p = 0; p < 8; p++) {
        float e0 = fast_exp2(st[2 * p]);
        float e1 = fast_exp2(st[2 * p + 1]);
        la0 += e0;
        la1 += e1;
        pk[p] = pkbf(e0, e1);
      }
      #pragma unroll
      for (int c16 = 0; c16 < 2; c16++) {
        frag8 bfr = mkfrag(pk[c16 * 4 + 0], pk[c16 * 4 + 1],
                           pk[c16 * 4 + 2], pk[c16 * 4 + 3]);
        __builtin_amdgcn_s_setprio(1);
        #pragma unroll
        for (int cm = 0; cm < 4; cm++) {
          int c = cm * 32 + lane31;
          int g = (kh * 4 + c16 * 2 + half) ^ (c & 7);
          frag8 a = *(const frag8*)(Vb + c * 128 + g * 16);
          o_[cm] = __builtin_amdgcn_mfma_f32_32x32x16_bf16(a, bfr, o_[cm], 0, 0, 0);
        }
        __builtin_amdgcn_s_setprio(0);
      }
    }
  };

  stage(0, A0);   // tile 0
  stage(64, A1);  // tile 1
  #pragma unroll 1
  for (int j = 0; j < 8; j++) {
    const int k0 = j * 256;
    __syncthreads();                  // A-pair loads landed; B-pair free
    stage(k0 + 128, B0);              // tiles 4j+2, 4j+3
    stage(k0 + 192, B1);
    compute(A0);                      // tiles 4j, 4j+1
    compute(A1);
    __syncthreads();                  // B-pair loads landed; A-pair free
    if (j < 7) {
      stage(k0 + 256, A0);            // tiles 4j+4, 4j+5
      stage(k0 + 320, A1);
    }
    compute(B0);                      // tiles 4j+2, 4j+3
    compute(B1);
  }

  // per-q l: lane's partial covers half the k-slots; partner (xor 32) holds the rest
  float l_acc = la0 + la1;
  float lt = l_acc + __shfl_xor(l_acc, 32);

  // ---- fused combine + LayerNorm epilogue ----
  // odd half-head waves publish O (f32, XOR-swizzled 16B slots: conflict-free) and l.
  // epi aliases A0/A1: last bufA read was before the loop's final __syncthreads — safe.
  if (hsel == 1) {
    if (half == 0) epi_l[qloc] = lt;
    #pragma unroll
    for (int cm = 0; cm < 4; cm++)
      #pragma unroll
      for (int g = 0; g < 4; g++) {
        int c = cm * 32 + g * 8 + half * 4;
        int pch = (c >> 2) ^ (qloc & 31);
        *(f32x4*)&epi[qloc * 128 + pch * 4] =
            (f32x4){o_[cm][4 * g + 0], o_[cm][4 * g + 1],
                    o_[cm][4 * g + 2], o_[cm][4 * g + 3]};
      }
  }
  __syncthreads();
  if (hsel == 0) {
    const float rle = 1.0f / lt;
    const float rlo = 1.0f / epi_l[qloc];
    float sum = 0.f, ss = 0.f;
    #pragma unroll
    for (int cm = 0; cm < 4; cm++)
      #pragma unroll
      for (int g = 0; g < 4; g++) {
        int c = cm * 32 + g * 8 + half * 4;
        int pch = (c >> 2) ^ (qloc & 31);
        f32x4 ov = *(const f32x4*)&epi[qloc * 128 + pch * 4];
        #pragma unroll
        for (int j = 0; j < 4; j++) {
          float v = o_[cm][4 * g + j] * rle - lam * ov[j] * rlo;
          o_[cm][4 * g + j] = v;
          sum += v;
          ss += v * v;
        }
      }
    sum += __shfl_xor(sum, 32); // lane pair (l, l+32) covers all 128 channels of q
    ss += __shfl_xor(ss, 32);
    float mu = sum * (1.0f / 128.0f);
    float var = ss * (1.0f / 128.0f) - mu * mu;
    float rr = rsqrtf(var + 1e-5f);
    int q = qb * 128 + qloc;
    ushort* ob = onorm + ((size_t)(b * N_ + q)) * E_ + h * 128;
    #pragma unroll
    for (int cm = 0; cm < 4; cm++)
      #pragma unroll
      for (int g = 0; g < 4; g++) {
        int c = cm * 32 + g * 8 + half * 4;
        float4 g4 = *(const float4*)&ln_g[c];
        float4 b4 = *(const float4*)&ln_b[c];
        float v0 = (o_[cm][4 * g + 0] - mu) * rr * g4.x + b4.x;
        float v1 = (o_[cm][4 * g + 1] - mu) * rr * g4.y + b4.y;
        float v2 = (o_[cm][4 * g + 2] - mu) * rr * g4.z + b4.z;
        float v3 = (o_[cm][4 * g + 3] - mu) * rr * g4.w + b4.w;
        uint2 pv;
        pv.x = pkbf(v0, v1);
        pv.y = pkbf(v2, v3);
        *(uint2*)(ob + c) = pv;
      }
  }
}

// ---------------- launch ----------------
extern "C" void kernel_launch(void* const* d_in, const int* in_sizes, int n_in,
                              void* d_out, int out_size, void* d_ws, size_t ws_size,
                              hipStream_t stream) {
  const float* x    = (const float*)d_in[0];
  const float* Wq   = (const float*)d_in[1];
  const float* Wk   = (const float*)d_in[2];
  const float* Wv   = (const float*)d_in[3];
  const float* Wo   = (const float*)d_in[4];
  const float* lq1  = (const float*)d_in[5];
  const float* lk1  = (const float*)d_in[6];
  const float* lq2  = (const float*)d_in[7];
  const float* lk2  = (const float*)d_in[8];
  const float* ln_g = (const float*)d_in[9];
  const float* ln_b = (const float*)d_in[10];
  float* out = (float*)d_out;

  const size_t MN = (size_t)B_ * N_ * E_; // 4194304
  ushort* xb    = (ushort*)d_ws;          // bf16 x              (8 MB)
  ushort* wqkvt = xb + MN;                // bf16 [Wq;Wk;Wv]^T   (6 MB)
  ushort* wot   = wqkvt + 3 * 1048576;    // bf16 Wo^T           (2 MB)
  ushort* qkb   = wot + 1048576;          // bf16 qk [4096][2048] (16 MB)
  ushort* vtb   = qkb + (size_t)4096 * 2048; // bf16 v^T [1024][4096] (8 MB)
  float*  lam   = (float*)(vtb + MN);
  ushort* onorm = xb;                     // reuse x buffer after the projection gemm

  prep_kernel<<<dim3(3073), 256, 0, stream>>>(x, Wq, Wk, Wv, Wo, lq1, lk1, lq2, lk2,
                                              xb, wqkvt, wot, lam);

  // fused QK + V^T projection in ONE launch (768 blocks = 3 blocks/CU), XCD-chunked
  gemm_qkv<<<dim3(768), 256, 0, stream>>>(xb, wqkvt, qkb, vtb, 0.125f * LOG2E);

  // paired-half-head flash with fused combine+LN (256 blocks = 1/CU), 2-tile barrier phases
  flash_kernel<<<dim3(256), 512, 0, stream>>>(qkb, vtb, lam, ln_g, ln_b, onorm);

  gemm_out<<<dim3(8, 64), 256, 0, stream>>>(onorm, wot, out);
}

// Round 12
// 207.736 us; speedup vs baseline: 1.0192x; 1.0192x over previous
//
#include <hip/hip_runtime.h>
#include <hip/hip_bf16.h>
#include <math.h>

#define B_ 2
#define N_ 2048
#define E_ 1024
#define H_ 8

typedef __attribute__((ext_vector_type(8))) short frag8;       // 8 bf16 (4 VGPRs)
typedef __attribute__((ext_vector_type(4))) float f32x4;
typedef __attribute__((ext_vector_type(16))) float f32x16;
typedef __attribute__((ext_vector_type(8))) unsigned short u16x8;

constexpr float LAM_INIT = 0.7836057665316245f; // 0.8 - 0.6*exp(-0.3*12)
constexpr float LOG2E = 1.4426950408889634f;
constexpr float EXP2_GUARD = -23.083120654f;    // -16 * log2(e)

static __device__ __forceinline__ float fast_exp2(float x) {
#if __has_builtin(__builtin_amdgcn_exp2f)
  return __builtin_amdgcn_exp2f(x);
#else
  return exp2f(x);
#endif
}

static __device__ __forceinline__ ushort f2bf(float f) {
  union { float f; unsigned u; } v; v.f = f;
  unsigned r = (v.u + 0x7FFFu + ((v.u >> 16) & 1u)) >> 16;
  return (ushort)r;
}

static __device__ __forceinline__ unsigned pkbf(float a, float b) {
  __hip_bfloat162 h = __float22bfloat162_rn(make_float2(a, b));
  return *(unsigned*)&h;
}

static __device__ __forceinline__ void async16(const void* g, void* l) {
  __builtin_amdgcn_global_load_lds((const __attribute__((address_space(1))) void*)g,
                                   (__attribute__((address_space(3))) void*)l, 16, 0, 0);
}

// Build the PV B-frag from 4 packed-bf16 dwords using v_permlane32_swap_b32
// (VALU pipe) instead of 2x __shfl_xor(32) (LDS pipe ds_bpermute) + 8 cndmask.
// permlane32_swap(a,b): r0 = {a.lo32, b.lo32}, r1 = {a.hi32, b.hi32}  (verified R1-R11)
static __device__ __forceinline__ frag8 mkfrag(unsigned p0, unsigned p1,
                                               unsigned p2, unsigned p3) {
  auto r02 = __builtin_amdgcn_permlane32_swap((int)p0, (int)p2, false, false);
  auto r13 = __builtin_amdgcn_permlane32_swap((int)p1, (int)p3, false, false);
  union { unsigned u[4]; frag8 f; } u;
  u.u[0] = (unsigned)r02[0];
  u.u[1] = (unsigned)r13[0];
  u.u[2] = (unsigned)r02[1];
  u.u[3] = (unsigned)r13[1];
  return u.f;
}

// ---------------- fused prep: cast x -> bf16 | 4x weight transpose+cast | lambda ----------------
__global__ __launch_bounds__(256) void prep_kernel(
    const float* __restrict__ x,
    const float* __restrict__ Wq, const float* __restrict__ Wk,
    const float* __restrict__ Wv, const float* __restrict__ Wo,
    const float* __restrict__ lq1, const float* __restrict__ lk1,
    const float* __restrict__ lq2, const float* __restrict__ lk2,
    ushort* __restrict__ xb, ushort* __restrict__ wqkvt, ushort* __restrict__ wot,
    float* __restrict__ lam_out) {
  __shared__ ushort t[64][72];
  const int bx = blockIdx.x;
  const int tid = threadIdx.x;
  if (bx < 2048) {
    // cast x (8 elems/thread)
    int i = bx * 256 + tid;
    const float4* sp = (const float4*)x + (size_t)i * 2;
    float4 a = sp[0], b = sp[1];
    u16x8 o;
    o[0] = f2bf(a.x); o[1] = f2bf(a.y); o[2] = f2bf(a.z); o[3] = f2bf(a.w);
    o[4] = f2bf(b.x); o[5] = f2bf(b.y); o[6] = f2bf(b.z); o[7] = f2bf(b.w);
    *(u16x8*)(xb + (size_t)i * 8) = o;
  } else if (bx < 3072) {
    int idx = bx - 2048;
    int sel = idx >> 8, rem = idx & 255;
    const float* W = (sel == 0) ? Wq : (sel == 1) ? Wk : (sel == 2) ? Wv : Wo;
    ushort* Wt = (sel < 3) ? (wqkvt + (size_t)sel * 1048576) : wot;
    const int c0 = (rem & 15) * 64, r0 = (rem >> 4) * 64;
    {
      int r = tid >> 2, cc = (tid & 3) * 16;
      const float* sp = W + (size_t)(r0 + r) * 1024 + c0 + cc;
      #pragma unroll
      for (int j = 0; j < 4; j++) {
        float4 a = *(const float4*)(sp + j * 4);
        t[cc + j * 4 + 0][r] = f2bf(a.x);
        t[cc + j * 4 + 1][r] = f2bf(a.y);
        t[cc + j * 4 + 2][r] = f2bf(a.z);
        t[cc + j * 4 + 3][r] = f2bf(a.w);
      }
    }
    __syncthreads();
    int c = tid >> 2, rr = (tid & 3) * 16;
    ushort* dp = Wt + (size_t)(c0 + c) * 1024 + r0 + rr;
    *(u16x8*)dp = *(u16x8*)&t[c][rr];
    *(u16x8*)(dp + 8) = *(u16x8*)&t[c][rr + 8];
  } else {
    if (tid < 64) {
      float t1 = lq1[tid] * lk1[tid];
      float t2 = lq2[tid] * lk2[tid];
      #pragma unroll
      for (int off = 32; off > 0; off >>= 1) {
        t1 += __shfl_down(t1, off);
        t2 += __shfl_down(t2, off);
      }
      if (tid == 0) lam_out[0] = expf(t1) - expf(t2) + LAM_INIT;
    }
  }
}

// ---------------- fused QK + V^T projection GEMM, 256x256 tile, single-barrier dbuf -----------
// R12 REWRITE: flash's proven single-barrier schedule (R2..R11) applied to gemm_qkv with a
// compute phase LONG enough to cover load latency — R7 failed at BK=32 (16-MFMA phase < L2
// latency); here each tile = 64 MFMA + 32 ds_read per wave (~600+ cyc cover), so the one
// __syncthreads per K-tile drains loads issued a FULL TILE earlier (cheap).
// Geometry: BM=BN=256, BK=64, 512 thr = 8 waves (2 Mx4 N), per-wave 128x64 out, acc[8][4].
// LDS 2 x (A 32K + B 32K) = 128 KB -> 1 block/CU. B-frags held in regs (8/tile), A streamed.
// R8-proven XOR swizzle (slot ^= row&7, 16B slots) on BOTH sides (rule #21): pre-swizzled
// global source in stage, XOR'd slot on frag reads. Frag formulas / operand order / C-mapping
// identical to the proven 128^2 kernel. Grid 192 = 128 QK (16x8) + 64 V (4x16), XCD-chunked.
// id < 128:  qkb[4096][2048] = xb @ [Wq;Wk]^T (q cols scaled);  else vtb[1024][4096] = Wv^T@xb^T.
// Pre-registered: absmax fail => mapping bug, revert; pass but e2e >= 211 => underfill, revert.
__global__ __launch_bounds__(512, 2) void gemm_qkv(const ushort* __restrict__ xb,
                                                   const ushort* __restrict__ wqkvt,
                                                   ushort* __restrict__ qkb,
                                                   ushort* __restrict__ vtb, float qscale) {
  __shared__ char smem[131072]; // buf0 | buf1, each [A 32768 | B 32768]
  const int id0 = blockIdx.x;
  const int id = (id0 & 7) * 24 + (id0 >> 3); // XCD-chunk remap (bijective, 192 = 8*24)
  const ushort* Ag; const ushort* Bg; ushort* C;
  int m0, n0, ldc;
  float sc;
  if (id < 128) {
    m0 = (id >> 3) * 256; n0 = (id & 7) * 256;
    Ag = xb; Bg = wqkvt; C = qkb; ldc = 2048;
    sc = (n0 < 1024) ? qscale : 1.0f;
  } else {
    int id2 = id - 128;
    m0 = (id2 & 3) * 256; n0 = (id2 >> 2) * 256;
    Ag = wqkvt + 2 * 1048576; Bg = xb; C = vtb; ldc = 4096;
    sc = 1.0f;
  }
  const int tid = threadIdx.x;
  const int w = tid >> 6, l = tid & 63;
  const int quad = l >> 4, col16 = l & 15;
  const int wr128 = (w >> 2) * 128; // wave row-block (2)
  const int wc64 = (w & 3) * 64;    // wave col-block (4)

  f32x4 acc[8][4];
  #pragma unroll
  for (int mi = 0; mi < 8; mi++)
    #pragma unroll
    for (int nj = 0; nj < 4; nj++) acc[mi][nj] = (f32x4){0.f, 0.f, 0.f, 0.f};

  // stage one K-tile (A 256x64 + B 256x64 = 64KB), 8 async16/thread.
  // LDS dest linear (base + lane*16); global k pre-swizzled: k = k0 + (slot ^ (row&7))*8.
  auto stage = [&](int kt, char* buf) {
    const int k0 = kt * 64;
    #pragma unroll
    for (int rr = 0; rr < 4; rr++) {
      int e = rr * 512 + tid;           // 0..2047
      int row = e >> 3, slot = e & 7;
      int ksw = k0 + ((slot ^ (row & 7)) << 3);
      async16(Ag + (size_t)(m0 + row) * 1024 + ksw, buf + e * 16);
      async16(Bg + (size_t)(n0 + row) * 1024 + ksw, buf + 32768 + e * 16);
    }
  };

  auto compute = [&](const char* buf) {
    const char* Ab = buf;
    const char* Bb = buf + 32768;
    frag8 bf_[4][2]; // held across the tile: nj x kk
    #pragma unroll
    for (int nj = 0; nj < 4; nj++) {
      int rb = wc64 + nj * 16 + col16;
      #pragma unroll
      for (int kk = 0; kk < 2; kk++) {
        int slot = kk * 4 + quad;
        bf_[nj][kk] = *(const frag8*)(Bb + rb * 128 + ((slot ^ (rb & 7)) << 4));
      }
    }
    __builtin_amdgcn_s_setprio(1);
    #pragma unroll
    for (int mi = 0; mi < 8; mi++) {
      int ra = wr128 + mi * 16 + col16;
      frag8 a0 = *(const frag8*)(Ab + ra * 128 + ((quad ^ (ra & 7)) << 4));
      frag8 a1 = *(const frag8*)(Ab + ra * 128 + (((4 + quad) ^ (ra & 7)) << 4));
      #pragma unroll
      for (int nj = 0; nj < 4; nj++) {
        acc[mi][nj] = __builtin_amdgcn_mfma_f32_16x16x32_bf16(a0, bf_[nj][0], acc[mi][nj], 0, 0, 0);
        acc[mi][nj] = __builtin_amdgcn_mfma_f32_16x16x32_bf16(a1, bf_[nj][1], acc[mi][nj], 0, 0, 0);
      }
    }
    __builtin_amdgcn_s_setprio(0);
  };

  char* buf0 = smem;
  char* buf1 = smem + 65536;
  stage(0, buf0);
  #pragma unroll 1
  for (int kt = 0; kt < 16; kt++) {
    char* cur = (kt & 1) ? buf1 : buf0;
    char* nxt = (kt & 1) ? buf0 : buf1;
    __syncthreads();               // tile kt loads landed (issued 1 full tile ago); nxt free
    if (kt < 15) stage(kt + 1, nxt);
    compute(cur);
  }

  #pragma unroll
  for (int mi = 0; mi < 8; mi++)
    #pragma unroll
    for (int r = 0; r < 4; r++) {
      int m = m0 + wr128 + mi * 16 + quad * 4 + r;
      #pragma unroll
      for (int nj = 0; nj < 4; nj++) {
        int n = n0 + wc64 + nj * 16 + col16;
        C[(size_t)m * ldc + n] = f2bf(acc[mi][nj][r] * sc);
      }
    }
}

// ---------------- output projection GEMM, 64x128 tiles (512 blocks = 2/CU) ----------------
__global__ __launch_bounds__(256) void gemm_out(const ushort* __restrict__ A,
                                                const ushort* __restrict__ Bt,
                                                float* __restrict__ Cp) {
  __shared__ ushort As[2048]; // 64 rows x 32, 4 KB
  __shared__ ushort Bs[4096]; // 128 rows x 32, 8 KB
  const int tid = threadIdx.x;
  const int w = tid >> 6, l = tid & 63;
  const int quad = l >> 4, col16 = l & 15;
  const int m0 = blockIdx.y * 64, n0 = blockIdx.x * 128;
  const int wm = (w & 1) * 32, wn = (w >> 1) * 64;
  const int lrow = l >> 2, lcol = (l & 3) * 8;

  f32x4 acc[2][4];
  #pragma unroll
  for (int mt = 0; mt < 2; mt++)
    #pragma unroll
    for (int nt = 0; nt < 4; nt++) acc[mt][nt] = (f32x4){0.f, 0.f, 0.f, 0.f};

  for (int k0 = 0; k0 < 1024; k0 += 32) {
    __syncthreads();
    #pragma unroll
    for (int i = 0; i < 3; i++) {
      int s = w * 3 + i; // 0..11, wave-uniform
      if (s < 4) {
        const ushort* gp = A + (size_t)(m0 + s * 16 + lrow) * 1024 + k0 + lcol;
        async16(gp, (char*)As + s * 1024);
      } else {
        int s2 = s - 4;
        const ushort* gp = Bt + (size_t)(n0 + s2 * 16 + lrow) * 1024 + k0 + lcol;
        async16(gp, (char*)Bs + s2 * 1024);
      }
    }
    __syncthreads();
    frag8 af[2], bfr[4];
    #pragma unroll
    for (int mt = 0; mt < 2; mt++)
      af[mt] = *(const frag8*)((const char*)As + (wm + mt * 16 + col16) * 64 + quad * 16);
    #pragma unroll
    for (int nt = 0; nt < 4; nt++)
      bfr[nt] = *(const frag8*)((const char*)Bs + (wn + nt * 16 + col16) * 64 + quad * 16);
    #pragma unroll
    for (int mt = 0; mt < 2; mt++)
      #pragma unroll
      for (int nt = 0; nt < 4; nt++)
        acc[mt][nt] = __builtin_amdgcn_mfma_f32_16x16x32_bf16(af[mt], bfr[nt], acc[mt][nt], 0, 0, 0);
  }

  #pragma unroll
  for (int mt = 0; mt < 2; mt++)
    #pragma unroll
    for (int r = 0; r < 4; r++) {
      int m = m0 + wm + mt * 16 + quad * 4 + r;
      #pragma unroll
      for (int nt = 0; nt < 4; nt++) {
        int n = n0 + wn + nt * 16 + col16;
        Cp[(size_t)m * 1024 + n] = acc[mt][nt][r];
      }
    }
}

// ---------------- MFMA flash attention, paired half-heads, 2-TILE BARRIER PHASES ---------------
// R11 best (66.9us): 256 blocks x 512 thr = 1/CU, R4 compute, TWO tiles per barrier phase
// (4 buffers). Frozen this round for clean attribution of the gemm_qkv rewrite.
__global__ __launch_bounds__(512, 2) void flash_kernel(const ushort* __restrict__ qk,
                                                       const ushort* __restrict__ vt,
                                                       const float* __restrict__ lam_p,
                                                       const float* __restrict__ ln_g,
                                                       const float* __restrict__ ln_b,
                                                       ushort* __restrict__ onorm) {
  // XCD-chunked remap: L = r + 8*s -> hb = r + 8*(s&1), qb = s>>1 (bijective).
  const int L = blockIdx.x;
  const int hb = (L & 7) | (((L >> 3) & 1) << 3); // 0..15
  const int qb = L >> 4;                          // 0..15
  const int h = hb & 7, b = hb >> 3;

  const int tid = threadIdx.x;
  const int w = tid >> 6;                 // 0..7
  const int hsel = w >> 2;                // 0: even half-head, 1: odd
  const int h2 = 2 * h + hsel;
  const int lane31 = tid & 31, half = (tid & 63) >> 5;
  const int qloc = (w & 3) * 32 + lane31; // q-row within block's 128
  const int i0 = qb * 128 + (w & 3) * 32; // wave's first q-row (global)

  __shared__ char smem[131584];
  char* A0 = smem;              // [K0 8K | K1 8K | V 16K] per tile slot
  char* A1 = smem + 32768;
  char* B0 = smem + 65536;
  char* B1 = smem + 98304;
  float* epi = (float*)smem;    // 64 KB O-exchange, aliases A0+A1 (used after final barrier)
  float* epi_l = (float*)(smem + 131072); // 128 floats

  const float lam = lam_p[0];

  // hoisted Q B-frags (per-wave, own half-head)
  frag8 qf[4];
  #pragma unroll
  for (int chk = 0; chk < 4; chk++) {
    const ushort* qp = qk + (size_t)(b * N_ + i0 + lane31) * 2048 +
                       h2 * 64 + chk * 16 + half * 8;
    qf[chk] = *(const frag8*)qp;
  }

  f32x16 o_[4];
  #pragma unroll
  for (int cm = 0; cm < 4; cm++)
    #pragma unroll
    for (int i = 0; i < 16; i++) o_[cm][i] = 0.f;
  float la0 = 0.f, la1 = 0.f;

  // stage one 64-k tile: K(2h) 8KB + K(2h+1) 8KB + V 16KB = 32KB, 4 async16/thread.
  // LDS dest linear (global source pre-swizzled) per rule #21.
  auto stage = [&](int k0, char* buf) {
    {
      int row = tid >> 3, sch = (tid & 7) ^ (row & 7);
      const ushort* kg = qk + (size_t)(b * N_ + k0 + row) * 2048 + 1024 + (2 * h) * 64 + sch * 8;
      async16(kg, buf + w * 1024);
    }
    {
      int row = tid >> 3, sch = (tid & 7) ^ (row & 7);
      const ushort* kg = qk + (size_t)(b * N_ + k0 + row) * 2048 + 1024 + (2 * h + 1) * 64 + sch * 8;
      async16(kg, buf + 8192 + w * 1024);
    }
    #pragma unroll
    for (int it = 0; it < 2; it++) {
      int j = it * 512 + tid;
      int row = j >> 3, sch = (j & 7) ^ (row & 7);
      const ushort* vg = vt + (size_t)(h * 128 + row) * 4096 + b * N_ + k0 + sch * 8;
      async16(vg, buf + 16384 + it * 8192 + w * 1024);
    }
  };

  auto compute = [&](const char* buf) {
    const char* Kb = buf + hsel * 8192;
    const char* Vb = buf + 16384;
    #pragma unroll
    for (int kh = 0; kh < 2; kh++) {
      f32x16 st;
      #pragma unroll
      for (int i = 0; i < 16; i++) st[i] = EXP2_GUARD;
      const int r = kh * 32 + lane31;
      __builtin_amdgcn_s_setprio(1);
      #pragma unroll
      for (int chk = 0; chk < 4; chk++) {
        frag8 a = *(const frag8*)(Kb + r * 128 + (((chk << 1) | half) ^ (r & 7)) * 16);
        st = __builtin_amdgcn_mfma_f32_32x32x16_bf16(a, qf[chk], st, 0, 0, 0);
      }
      __builtin_amdgcn_s_setprio(0);
      unsigned pk[8];
      #pragma unroll
      for (int p = 0; p < 8; p++) {
        float e0 = fast_exp2(st[2 * p]);
        float e1 = fast_exp2(st[2 * p + 1]);
        la0 += e0;
        la1 += e1;
        pk[p] = pkbf(e0, e1);
      }
      #pragma unroll
      for (int c16 = 0; c16 < 2; c16++) {
        frag8 bfr = mkfrag(pk[c16 * 4 + 0], pk[c16 * 4 + 1],
                           pk[c16 * 4 + 2], pk[c16 * 4 + 3]);
        __builtin_amdgcn_s_setprio(1);
        #pragma unroll
        for (int cm = 0; cm < 4; cm++) {
          int c = cm * 32 + lane31;
          int g = (kh * 4 + c16 * 2 + half) ^ (c & 7);
          frag8 a = *(const frag8*)(Vb + c * 128 + g * 16);
          o_[cm] = __builtin_amdgcn_mfma_f32_32x32x16_bf16(a, bfr, o_[cm], 0, 0, 0);
        }
        __builtin_amdgcn_s_setprio(0);
      }
    }
  };

  stage(0, A0);   // tile 0
  stage(64, A1);  // tile 1
  #pragma unroll 1
  for (int j = 0; j < 8; j++) {
    const int k0 = j * 256;
    __syncthreads();                  // A-pair loads landed; B-pair free
    stage(k0 + 128, B0);              // tiles 4j+2, 4j+3
    stage(k0 + 192, B1);
    compute(A0);                      // tiles 4j, 4j+1
    compute(A1);
    __syncthreads();                  // B-pair loads landed; A-pair free
    if (j < 7) {
      stage(k0 + 256, A0);            // tiles 4j+4, 4j+5
      stage(k0 + 320, A1);
    }
    compute(B0);                      // tiles 4j+2, 4j+3
    compute(B1);
  }

  // per-q l: lane's partial covers half the k-slots; partner (xor 32) holds the rest
  float l_acc = la0 + la1;
  float lt = l_acc + __shfl_xor(l_acc, 32);

  // ---- fused combine + LayerNorm epilogue ----
  // odd half-head waves publish O (f32, XOR-swizzled 16B slots: conflict-free) and l.
  // epi aliases A0/A1: last bufA read was before the loop's final __syncthreads — safe.
  if (hsel == 1) {
    if (half == 0) epi_l[qloc] = lt;
    #pragma unroll
    for (int cm = 0; cm < 4; cm++)
      #pragma unroll
      for (int g = 0; g < 4; g++) {
        int c = cm * 32 + g * 8 + half * 4;
        int pch = (c >> 2) ^ (qloc & 31);
        *(f32x4*)&epi[qloc * 128 + pch * 4] =
            (f32x4){o_[cm][4 * g + 0], o_[cm][4 * g + 1],
                    o_[cm][4 * g + 2], o_[cm][4 * g + 3]};
      }
  }
  __syncthreads();
  if (hsel == 0) {
    const float rle = 1.0f / lt;
    const float rlo = 1.0f / epi_l[qloc];
    float sum = 0.f, ss = 0.f;
    #pragma unroll
    for (int cm = 0; cm < 4; cm++)
      #pragma unroll
      for (int g = 0; g < 4; g++) {
        int c = cm * 32 + g * 8 + half * 4;
        int pch = (c >> 2) ^ (qloc & 31);
        f32x4 ov = *(const f32x4*)&epi[qloc * 128 + pch * 4];
        #pragma unroll
        for (int j = 0; j < 4; j++) {
          float v = o_[cm][4 * g + j] * rle - lam * ov[j] * rlo;
          o_[cm][4 * g + j] = v;
          sum += v;
          ss += v * v;
        }
      }
    sum += __shfl_xor(sum, 32); // lane pair (l, l+32) covers all 128 channels of q
    ss += __shfl_xor(ss, 32);
    float mu = sum * (1.0f / 128.0f);
    float var = ss * (1.0f / 128.0f) - mu * mu;
    float rr = rsqrtf(var + 1e-5f);
    int q = qb * 128 + qloc;
    ushort* ob = onorm + ((size_t)(b * N_ + q)) * E_ + h * 128;
    #pragma unroll
    for (int cm = 0; cm < 4; cm++)
      #pragma unroll
      for (int g = 0; g < 4; g++) {
        int c = cm * 32 + g * 8 + half * 4;
        float4 g4 = *(const float4*)&ln_g[c];
        float4 b4 = *(const float4*)&ln_b[c];
        float v0 = (o_[cm][4 * g + 0] - mu) * rr * g4.x + b4.x;
        float v1 = (o_[cm][4 * g + 1] - mu) * rr * g4.y + b4.y;
        float v2 = (o_[cm][4 * g + 2] - mu) * rr * g4.z + b4.z;
        float v3 = (o_[cm][4 * g + 3] - mu) * rr * g4.w + b4.w;
        uint2 pv;
        pv.x = pkbf(v0, v1);
        pv.y = pkbf(v2, v3);
        *(uint2*)(ob + c) = pv;
      }
  }
}

// ---------------- launch ----------------
extern "C" void kernel_launch(void* const* d_in, const int* in_sizes, int n_in,
                              void* d_out, int out_size, void* d_ws, size_t ws_size,
                              hipStream_t stream) {
  const float* x    = (const float*)d_in[0];
  const float* Wq   = (const float*)d_in[1];
  const float* Wk   = (const float*)d_in[2];
  const float* Wv   = (const float*)d_in[3];
  const float* Wo   = (const float*)d_in[4];
  const float* lq1  = (const float*)d_in[5];
  const float* lk1  = (const float*)d_in[6];
  const float* lq2  = (const float*)d_in[7];
  const float* lk2  = (const float*)d_in[8];
  const float* ln_g = (const float*)d_in[9];
  const float* ln_b = (const float*)d_in[10];
  float* out = (float*)d_out;

  const size_t MN = (size_t)B_ * N_ * E_; // 4194304
  ushort* xb    = (ushort*)d_ws;          // bf16 x              (8 MB)
  ushort* wqkvt = xb + MN;                // bf16 [Wq;Wk;Wv]^T   (6 MB)
  ushort* wot   = wqkvt + 3 * 1048576;    // bf16 Wo^T           (2 MB)
  ushort* qkb   = wot + 1048576;          // bf16 qk [4096][2048] (16 MB)
  ushort* vtb   = qkb + (size_t)4096 * 2048; // bf16 v^T [1024][4096] (8 MB)
  float*  lam   = (float*)(vtb + MN);
  ushort* onorm = xb;                     // reuse x buffer after the projection gemm

  prep_kernel<<<dim3(3073), 256, 0, stream>>>(x, Wq, Wk, Wv, Wo, lq1, lk1, lq2, lk2,
                                              xb, wqkvt, wot, lam);

  // fused QK + V^T projection, 256^2 tiles, single-barrier dbuf (192 blocks, XCD-chunked)
  gemm_qkv<<<dim3(192), 512, 0, stream>>>(xb, wqkvt, qkb, vtb, 0.125f * LOG2E);

  // paired-half-head flash with fused combine+LN (256 blocks = 1/CU), 2-tile barrier phases
  flash_kernel<<<dim3(256), 512, 0, stream>>>(qkb, vtb, lam, ln_g, ln_b, onorm);

  gemm_out<<<dim3(8, 64), 256, 0, stream>>>(onorm, wot, out);
}

// Round 13
// 193.509 us; speedup vs baseline: 1.0942x; 1.0735x over previous
//
#include <hip/hip_runtime.h>
#include <hip/hip_bf16.h>
#include <math.h>

#define B_ 2
#define N_ 2048
#define E_ 1024
#define H_ 8

typedef __attribute__((ext_vector_type(8))) short frag8;       // 8 bf16 (4 VGPRs)
typedef __attribute__((ext_vector_type(4))) float f32x4;
typedef __attribute__((ext_vector_type(16))) float f32x16;
typedef __attribute__((ext_vector_type(8))) unsigned short u16x8;

constexpr float LAM_INIT = 0.7836057665316245f; // 0.8 - 0.6*exp(-0.3*12)
constexpr float LOG2E = 1.4426950408889634f;
constexpr float EXP2_GUARD = -23.083120654f;    // -16 * log2(e)

static __device__ __forceinline__ float fast_exp2(float x) {
#if __has_builtin(__builtin_amdgcn_exp2f)
  return __builtin_amdgcn_exp2f(x);
#else
  return exp2f(x);
#endif
}

static __device__ __forceinline__ ushort f2bf(float f) {
  union { float f; unsigned u; } v; v.f = f;
  unsigned r = (v.u + 0x7FFFu + ((v.u >> 16) & 1u)) >> 16;
  return (ushort)r;
}

static __device__ __forceinline__ unsigned pkbf(float a, float b) {
  __hip_bfloat162 h = __float22bfloat162_rn(make_float2(a, b));
  return *(unsigned*)&h;
}

static __device__ __forceinline__ void async16(const void* g, void* l) {
  __builtin_amdgcn_global_load_lds((const __attribute__((address_space(1))) void*)g,
                                   (__attribute__((address_space(3))) void*)l, 16, 0, 0);
}

// Build the PV B-frag from 4 packed-bf16 dwords using v_permlane32_swap_b32
// (VALU pipe) instead of 2x __shfl_xor(32) (LDS pipe ds_bpermute) + 8 cndmask.
// permlane32_swap(a,b): r0 = {a.lo32, b.lo32}, r1 = {a.hi32, b.hi32}  (verified R1-R12)
static __device__ __forceinline__ frag8 mkfrag(unsigned p0, unsigned p1,
                                               unsigned p2, unsigned p3) {
  auto r02 = __builtin_amdgcn_permlane32_swap((int)p0, (int)p2, false, false);
  auto r13 = __builtin_amdgcn_permlane32_swap((int)p1, (int)p3, false, false);
  union { unsigned u[4]; frag8 f; } u;
  u.u[0] = (unsigned)r02[0];
  u.u[1] = (unsigned)r13[0];
  u.u[2] = (unsigned)r02[1];
  u.u[3] = (unsigned)r13[1];
  return u.f;
}

// ---------------- fused prep: cast x -> bf16 | 4x weight transpose+cast | lambda ----------------
__global__ __launch_bounds__(256) void prep_kernel(
    const float* __restrict__ x,
    const float* __restrict__ Wq, const float* __restrict__ Wk,
    const float* __restrict__ Wv, const float* __restrict__ Wo,
    const float* __restrict__ lq1, const float* __restrict__ lk1,
    const float* __restrict__ lq2, const float* __restrict__ lk2,
    ushort* __restrict__ xb, ushort* __restrict__ wqkvt, ushort* __restrict__ wot,
    float* __restrict__ lam_out) {
  __shared__ ushort t[64][72];
  const int bx = blockIdx.x;
  const int tid = threadIdx.x;
  if (bx < 2048) {
    // cast x (8 elems/thread)
    int i = bx * 256 + tid;
    const float4* sp = (const float4*)x + (size_t)i * 2;
    float4 a = sp[0], b = sp[1];
    u16x8 o;
    o[0] = f2bf(a.x); o[1] = f2bf(a.y); o[2] = f2bf(a.z); o[3] = f2bf(a.w);
    o[4] = f2bf(b.x); o[5] = f2bf(b.y); o[6] = f2bf(b.z); o[7] = f2bf(b.w);
    *(u16x8*)(xb + (size_t)i * 8) = o;
  } else if (bx < 3072) {
    int idx = bx - 2048;
    int sel = idx >> 8, rem = idx & 255;
    const float* W = (sel == 0) ? Wq : (sel == 1) ? Wk : (sel == 2) ? Wv : Wo;
    ushort* Wt = (sel < 3) ? (wqkvt + (size_t)sel * 1048576) : wot;
    const int c0 = (rem & 15) * 64, r0 = (rem >> 4) * 64;
    {
      int r = tid >> 2, cc = (tid & 3) * 16;
      const float* sp = W + (size_t)(r0 + r) * 1024 + c0 + cc;
      #pragma unroll
      for (int j = 0; j < 4; j++) {
        float4 a = *(const float4*)(sp + j * 4);
        t[cc + j * 4 + 0][r] = f2bf(a.x);
        t[cc + j * 4 + 1][r] = f2bf(a.y);
        t[cc + j * 4 + 2][r] = f2bf(a.z);
        t[cc + j * 4 + 3][r] = f2bf(a.w);
      }
    }
    __syncthreads();
    int c = tid >> 2, rr = (tid & 3) * 16;
    ushort* dp = Wt + (size_t)(c0 + c) * 1024 + r0 + rr;
    *(u16x8*)dp = *(u16x8*)&t[c][rr];
    *(u16x8*)(dp + 8) = *(u16x8*)&t[c][rr + 8];
  } else {
    if (tid < 64) {
      float t1 = lq1[tid] * lk1[tid];
      float t2 = lq2[tid] * lk2[tid];
      #pragma unroll
      for (int off = 32; off > 0; off >>= 1) {
        t1 += __shfl_down(t1, off);
        t2 += __shfl_down(t2, off);
      }
      if (tid == 0) lam_out[0] = expf(t1) - expf(t2) + LAM_INIT;
    }
  }
}

// ---------------- fused QK + V^T projection GEMM, 256x256 tile, single-barrier dbuf -----------
// R12-proven (dropped out of top-5): flash's single-barrier schedule with a 64-MFMA/wave
// compute phase (covers load latency — R7's BK=32 failure mode avoided). BM=BN=256, BK=64,
// 512 thr = 8 waves (2Mx4N), per-wave 128x64, acc[8][4]. LDS 2x64KB = 128KB -> 1 block/CU.
// XOR swizzle (R8 form) both-sides per rule #21. Grid 192 = 128 QK + 64 V, XCD-chunked.
__global__ __launch_bounds__(512, 2) void gemm_qkv(const ushort* __restrict__ xb,
                                                   const ushort* __restrict__ wqkvt,
                                                   ushort* __restrict__ qkb,
                                                   ushort* __restrict__ vtb, float qscale) {
  __shared__ char smem[131072]; // buf0 | buf1, each [A 32768 | B 32768]
  const int id0 = blockIdx.x;
  const int id = (id0 & 7) * 24 + (id0 >> 3); // XCD-chunk remap (bijective, 192 = 8*24)
  const ushort* Ag; const ushort* Bg; ushort* C;
  int m0, n0, ldc;
  float sc;
  if (id < 128) {
    m0 = (id >> 3) * 256; n0 = (id & 7) * 256;
    Ag = xb; Bg = wqkvt; C = qkb; ldc = 2048;
    sc = (n0 < 1024) ? qscale : 1.0f;
  } else {
    int id2 = id - 128;
    m0 = (id2 & 3) * 256; n0 = (id2 >> 2) * 256;
    Ag = wqkvt + 2 * 1048576; Bg = xb; C = vtb; ldc = 4096;
    sc = 1.0f;
  }
  const int tid = threadIdx.x;
  const int w = tid >> 6, l = tid & 63;
  const int quad = l >> 4, col16 = l & 15;
  const int wr128 = (w >> 2) * 128; // wave row-block (2)
  const int wc64 = (w & 3) * 64;    // wave col-block (4)

  f32x4 acc[8][4];
  #pragma unroll
  for (int mi = 0; mi < 8; mi++)
    #pragma unroll
    for (int nj = 0; nj < 4; nj++) acc[mi][nj] = (f32x4){0.f, 0.f, 0.f, 0.f};

  // stage one K-tile (A 256x64 + B 256x64 = 64KB), 8 async16/thread.
  // LDS dest linear (base + lane*16); global k pre-swizzled: k = k0 + (slot ^ (row&7))*8.
  auto stage = [&](int kt, char* buf) {
    const int k0 = kt * 64;
    #pragma unroll
    for (int rr = 0; rr < 4; rr++) {
      int e = rr * 512 + tid;           // 0..2047
      int row = e >> 3, slot = e & 7;
      int ksw = k0 + ((slot ^ (row & 7)) << 3);
      async16(Ag + (size_t)(m0 + row) * 1024 + ksw, buf + e * 16);
      async16(Bg + (size_t)(n0 + row) * 1024 + ksw, buf + 32768 + e * 16);
    }
  };

  auto compute = [&](const char* buf) {
    const char* Ab = buf;
    const char* Bb = buf + 32768;
    frag8 bf_[4][2]; // held across the tile: nj x kk
    #pragma unroll
    for (int nj = 0; nj < 4; nj++) {
      int rb = wc64 + nj * 16 + col16;
      #pragma unroll
      for (int kk = 0; kk < 2; kk++) {
        int slot = kk * 4 + quad;
        bf_[nj][kk] = *(const frag8*)(Bb + rb * 128 + ((slot ^ (rb & 7)) << 4));
      }
    }
    __builtin_amdgcn_s_setprio(1);
    #pragma unroll
    for (int mi = 0; mi < 8; mi++) {
      int ra = wr128 + mi * 16 + col16;
      frag8 a0 = *(const frag8*)(Ab + ra * 128 + ((quad ^ (ra & 7)) << 4));
      frag8 a1 = *(const frag8*)(Ab + ra * 128 + (((4 + quad) ^ (ra & 7)) << 4));
      #pragma unroll
      for (int nj = 0; nj < 4; nj++) {
        acc[mi][nj] = __builtin_amdgcn_mfma_f32_16x16x32_bf16(a0, bf_[nj][0], acc[mi][nj], 0, 0, 0);
        acc[mi][nj] = __builtin_amdgcn_mfma_f32_16x16x32_bf16(a1, bf_[nj][1], acc[mi][nj], 0, 0, 0);
      }
    }
    __builtin_amdgcn_s_setprio(0);
  };

  char* buf0 = smem;
  char* buf1 = smem + 65536;
  stage(0, buf0);
  #pragma unroll 1
  for (int kt = 0; kt < 16; kt++) {
    char* cur = (kt & 1) ? buf1 : buf0;
    char* nxt = (kt & 1) ? buf0 : buf1;
    __syncthreads();               // tile kt loads landed (issued 1 full tile ago); nxt free
    if (kt < 15) stage(kt + 1, nxt);
    compute(cur);
  }

  #pragma unroll
  for (int mi = 0; mi < 8; mi++)
    #pragma unroll
    for (int r = 0; r < 4; r++) {
      int m = m0 + wr128 + mi * 16 + quad * 4 + r;
      #pragma unroll
      for (int nj = 0; nj < 4; nj++) {
        int n = n0 + wc64 + nj * 16 + col16;
        C[(size_t)m * ldc + n] = f2bf(acc[mi][nj][r] * sc);
      }
    }
}

// ---------------- output projection GEMM, 64x128 tiles, 2-TILE PHASES + XCD chunk --------------
// R13: R11's proven 2-tile-per-barrier-phase schedule (4 buffers P0..P3, 12KB each = 48KB,
// 2 blocks/CU -> 96KB) applied to gemm_out: barrier count 64 -> 16, each load batch gets a
// full 2-tile 32-MFMA compute phase to land (the R7-failure condition avoided, R11/R12-style).
// Plus T1 XCD-chunk remap (512 = 8*64 bijective): each XCD gets 8 contiguous m-rows x all n
// -> A 1MB + B 2MB = 3MB L2-resident (default x-fastest order thrashed 8MB of A per XCD).
__global__ __launch_bounds__(256) void gemm_out(const ushort* __restrict__ A,
                                                const ushort* __restrict__ Bt,
                                                float* __restrict__ Cp) {
  __shared__ char smem[49152]; // P0..P3, each [A 4K | B 8K]
  const int id0 = blockIdx.x;
  const int id = (id0 & 7) * 64 + (id0 >> 3); // XCD-chunk remap (bijective, 512 = 8*64)
  const int m0 = (id >> 3) * 64, n0 = (id & 7) * 128;
  const int tid = threadIdx.x;
  const int w = tid >> 6, l = tid & 63;
  const int quad = l >> 4, col16 = l & 15;
  const int wm = (w & 1) * 32, wn = (w >> 1) * 64;
  const int lrow = l >> 2, lcol = (l & 3) * 8;

  f32x4 acc[2][4];
  #pragma unroll
  for (int mt = 0; mt < 2; mt++)
    #pragma unroll
    for (int nt = 0; nt < 4; nt++) acc[mt][nt] = (f32x4){0.f, 0.f, 0.f, 0.f};

  auto stage = [&](int kt, char* buf) {
    const int k0 = kt * 32;
    #pragma unroll
    for (int i = 0; i < 3; i++) {
      int s = w * 3 + i; // 0..11, wave-uniform
      if (s < 4) {
        const ushort* gp = A + (size_t)(m0 + s * 16 + lrow) * 1024 + k0 + lcol;
        async16(gp, buf + s * 1024);
      } else {
        int s2 = s - 4;
        const ushort* gp = Bt + (size_t)(n0 + s2 * 16 + lrow) * 1024 + k0 + lcol;
        async16(gp, buf + 4096 + s2 * 1024);
      }
    }
  };

  auto compute = [&](const char* buf) {
    const char* As_ = buf;
    const char* Bs_ = buf + 4096;
    frag8 af[2], bfr[4];
    #pragma unroll
    for (int mt = 0; mt < 2; mt++)
      af[mt] = *(const frag8*)(As_ + (wm + mt * 16 + col16) * 64 + quad * 16);
    #pragma unroll
    for (int nt = 0; nt < 4; nt++)
      bfr[nt] = *(const frag8*)(Bs_ + (wn + nt * 16 + col16) * 64 + quad * 16);
    __builtin_amdgcn_s_setprio(1);
    #pragma unroll
    for (int mt = 0; mt < 2; mt++)
      #pragma unroll
      for (int nt = 0; nt < 4; nt++)
        acc[mt][nt] = __builtin_amdgcn_mfma_f32_16x16x32_bf16(af[mt], bfr[nt], acc[mt][nt], 0, 0, 0);
    __builtin_amdgcn_s_setprio(0);
  };

  char* P0 = smem;
  char* P1 = smem + 12288;
  char* P2 = smem + 24576;
  char* P3 = smem + 36864;

  stage(0, P0); // tiles 0,1
  stage(1, P1);
  #pragma unroll 1
  for (int j = 0; j < 8; j++) {
    const int t = j * 4;
    __syncthreads();              // P0,P1 loads landed; P2,P3 free
    stage(t + 2, P2);             // tiles 4j+2, 4j+3 (always in range: t+3 <= 31)
    stage(t + 3, P3);
    compute(P0);                  // tiles 4j, 4j+1
    compute(P1);
    __syncthreads();              // P2,P3 loads landed; P0,P1 free
    if (j < 7) {
      stage(t + 4, P0);           // tiles 4j+4, 4j+5
      stage(t + 5, P1);
    }
    compute(P2);                  // tiles 4j+2, 4j+3
    compute(P3);
  }

  #pragma unroll
  for (int mt = 0; mt < 2; mt++)
    #pragma unroll
    for (int r = 0; r < 4; r++) {
      int m = m0 + wm + mt * 16 + quad * 4 + r;
      #pragma unroll
      for (int nt = 0; nt < 4; nt++) {
        int n = n0 + wn + nt * 16 + col16;
        Cp[(size_t)m * 1024 + n] = acc[mt][nt][r];
      }
    }
}

// ---------------- MFMA flash attention, paired half-heads, 2-TILE BARRIER PHASES ---------------
// R11 best (66.9-67.8us): 256 blocks x 512 thr = 1/CU, R4 compute, TWO tiles per barrier phase
// (4 buffers). Frozen.
__global__ __launch_bounds__(512, 2) void flash_kernel(const ushort* __restrict__ qk,
                                                       const ushort* __restrict__ vt,
                                                       const float* __restrict__ lam_p,
                                                       const float* __restrict__ ln_g,
                                                       const float* __restrict__ ln_b,
                                                       ushort* __restrict__ onorm) {
  // XCD-chunked remap: L = r + 8*s -> hb = r + 8*(s&1), qb = s>>1 (bijective).
  const int L = blockIdx.x;
  const int hb = (L & 7) | (((L >> 3) & 1) << 3); // 0..15
  const int qb = L >> 4;                          // 0..15
  const int h = hb & 7, b = hb >> 3;

  const int tid = threadIdx.x;
  const int w = tid >> 6;                 // 0..7
  const int hsel = w >> 2;                // 0: even half-head, 1: odd
  const int h2 = 2 * h + hsel;
  const int lane31 = tid & 31, half = (tid & 63) >> 5;
  const int qloc = (w & 3) * 32 + lane31; // q-row within block's 128
  const int i0 = qb * 128 + (w & 3) * 32; // wave's first q-row (global)

  __shared__ char smem[131584];
  char* A0 = smem;              // [K0 8K | K1 8K | V 16K] per tile slot
  char* A1 = smem + 32768;
  char* B0 = smem + 65536;
  char* B1 = smem + 98304;
  float* epi = (float*)smem;    // 64 KB O-exchange, aliases A0+A1 (used after final barrier)
  float* epi_l = (float*)(smem + 131072); // 128 floats

  const float lam = lam_p[0];

  // hoisted Q B-frags (per-wave, own half-head)
  frag8 qf[4];
  #pragma unroll
  for (int chk = 0; chk < 4; chk++) {
    const ushort* qp = qk + (size_t)(b * N_ + i0 + lane31) * 2048 +
                       h2 * 64 + chk * 16 + half * 8;
    qf[chk] = *(const frag8*)qp;
  }

  f32x16 o_[4];
  #pragma unroll
  for (int cm = 0; cm < 4; cm++)
    #pragma unroll
    for (int i = 0; i < 16; i++) o_[cm][i] = 0.f;
  float la0 = 0.f, la1 = 0.f;

  // stage one 64-k tile: K(2h) 8KB + K(2h+1) 8KB + V 16KB = 32KB, 4 async16/thread.
  // LDS dest linear (global source pre-swizzled) per rule #21.
  auto stage = [&](int k0, char* buf) {
    {
      int row = tid >> 3, sch = (tid & 7) ^ (row & 7);
      const ushort* kg = qk + (size_t)(b * N_ + k0 + row) * 2048 + 1024 + (2 * h) * 64 + sch * 8;
      async16(kg, buf + w * 1024);
    }
    {
      int row = tid >> 3, sch = (tid & 7) ^ (row & 7);
      const ushort* kg = qk + (size_t)(b * N_ + k0 + row) * 2048 + 1024 + (2 * h + 1) * 64 + sch * 8;
      async16(kg, buf + 8192 + w * 1024);
    }
    #pragma unroll
    for (int it = 0; it < 2; it++) {
      int j = it * 512 + tid;
      int row = j >> 3, sch = (j & 7) ^ (row & 7);
      const ushort* vg = vt + (size_t)(h * 128 + row) * 4096 + b * N_ + k0 + sch * 8;
      async16(vg, buf + 16384 + it * 8192 + w * 1024);
    }
  };

  auto compute = [&](const char* buf) {
    const char* Kb = buf + hsel * 8192;
    const char* Vb = buf + 16384;
    #pragma unroll
    for (int kh = 0; kh < 2; kh++) {
      f32x16 st;
      #pragma unroll
      for (int i = 0; i < 16; i++) st[i] = EXP2_GUARD;
      const int r = kh * 32 + lane31;
      __builtin_amdgcn_s_setprio(1);
      #pragma unroll
      for (int chk = 0; chk < 4; chk++) {
        frag8 a = *(const frag8*)(Kb + r * 128 + (((chk << 1) | half) ^ (r & 7)) * 16);
        st = __builtin_amdgcn_mfma_f32_32x32x16_bf16(a, qf[chk], st, 0, 0, 0);
      }
      __builtin_amdgcn_s_setprio(0);
      unsigned pk[8];
      #pragma unroll
      for (int p = 0; p < 8; p++) {
        float e0 = fast_exp2(st[2 * p]);
        float e1 = fast_exp2(st[2 * p + 1]);
        la0 += e0;
        la1 += e1;
        pk[p] = pkbf(e0, e1);
      }
      #pragma unroll
      for (int c16 = 0; c16 < 2; c16++) {
        frag8 bfr = mkfrag(pk[c16 * 4 + 0], pk[c16 * 4 + 1],
                           pk[c16 * 4 + 2], pk[c16 * 4 + 3]);
        __builtin_amdgcn_s_setprio(1);
        #pragma unroll
        for (int cm = 0; cm < 4; cm++) {
          int c = cm * 32 + lane31;
          int g = (kh * 4 + c16 * 2 + half) ^ (c & 7);
          frag8 a = *(const frag8*)(Vb + c * 128 + g * 16);
          o_[cm] = __builtin_amdgcn_mfma_f32_32x32x16_bf16(a, bfr, o_[cm], 0, 0, 0);
        }
        __builtin_amdgcn_s_setprio(0);
      }
    }
  };

  stage(0, A0);   // tile 0
  stage(64, A1);  // tile 1
  #pragma unroll 1
  for (int j = 0; j < 8; j++) {
    const int k0 = j * 256;
    __syncthreads();                  // A-pair loads landed; B-pair free
    stage(k0 + 128, B0);              // tiles 4j+2, 4j+3
    stage(k0 + 192, B1);
    compute(A0);                      // tiles 4j, 4j+1
    compute(A1);
    __syncthreads();                  // B-pair loads landed; A-pair free
    if (j < 7) {
      stage(k0 + 256, A0);            // tiles 4j+4, 4j+5
      stage(k0 + 320, A1);
    }
    compute(B0);                      // tiles 4j+2, 4j+3
    compute(B1);
  }

  // per-q l: lane's partial covers half the k-slots; partner (xor 32) holds the rest
  float l_acc = la0 + la1;
  float lt = l_acc + __shfl_xor(l_acc, 32);

  // ---- fused combine + LayerNorm epilogue ----
  // odd half-head waves publish O (f32, XOR-swizzled 16B slots: conflict-free) and l.
  // epi aliases A0/A1: last bufA read was before the loop's final __syncthreads — safe.
  if (hsel == 1) {
    if (half == 0) epi_l[qloc] = lt;
    #pragma unroll
    for (int cm = 0; cm < 4; cm++)
      #pragma unroll
      for (int g = 0; g < 4; g++) {
        int c = cm * 32 + g * 8 + half * 4;
        int pch = (c >> 2) ^ (qloc & 31);
        *(f32x4*)&epi[qloc * 128 + pch * 4] =
            (f32x4){o_[cm][4 * g + 0], o_[cm][4 * g + 1],
                    o_[cm][4 * g + 2], o_[cm][4 * g + 3]};
      }
  }
  __syncthreads();
  if (hsel == 0) {
    const float rle = 1.0f / lt;
    const float rlo = 1.0f / epi_l[qloc];
    float sum = 0.f, ss = 0.f;
    #pragma unroll
    for (int cm = 0; cm < 4; cm++)
      #pragma unroll
      for (int g = 0; g < 4; g++) {
        int c = cm * 32 + g * 8 + half * 4;
        int pch = (c >> 2) ^ (qloc & 31);
        f32x4 ov = *(const f32x4*)&epi[qloc * 128 + pch * 4];
        #pragma unroll
        for (int j = 0; j < 4; j++) {
          float v = o_[cm][4 * g + j] * rle - lam * ov[j] * rlo;
          o_[cm][4 * g + j] = v;
          sum += v;
          ss += v * v;
        }
      }
    sum += __shfl_xor(sum, 32); // lane pair (l, l+32) covers all 128 channels of q
    ss += __shfl_xor(ss, 32);
    float mu = sum * (1.0f / 128.0f);
    float var = ss * (1.0f / 128.0f) - mu * mu;
    float rr = rsqrtf(var + 1e-5f);
    int q = qb * 128 + qloc;
    ushort* ob = onorm + ((size_t)(b * N_ + q)) * E_ + h * 128;
    #pragma unroll
    for (int cm = 0; cm < 4; cm++)
      #pragma unroll
      for (int g = 0; g < 4; g++) {
        int c = cm * 32 + g * 8 + half * 4;
        float4 g4 = *(const float4*)&ln_g[c];
        float4 b4 = *(const float4*)&ln_b[c];
        float v0 = (o_[cm][4 * g + 0] - mu) * rr * g4.x + b4.x;
        float v1 = (o_[cm][4 * g + 1] - mu) * rr * g4.y + b4.y;
        float v2 = (o_[cm][4 * g + 2] - mu) * rr * g4.z + b4.z;
        float v3 = (o_[cm][4 * g + 3] - mu) * rr * g4.w + b4.w;
        uint2 pv;
        pv.x = pkbf(v0, v1);
        pv.y = pkbf(v2, v3);
        *(uint2*)(ob + c) = pv;
      }
  }
}

// ---------------- launch ----------------
extern "C" void kernel_launch(void* const* d_in, const int* in_sizes, int n_in,
                              void* d_out, int out_size, void* d_ws, size_t ws_size,
                              hipStream_t stream) {
  const float* x    = (const float*)d_in[0];
  const float* Wq   = (const float*)d_in[1];
  const float* Wk   = (const float*)d_in[2];
  const float* Wv   = (const float*)d_in[3];
  const float* Wo   = (const float*)d_in[4];
  const float* lq1  = (const float*)d_in[5];
  const float* lk1  = (const float*)d_in[6];
  const float* lq2  = (const float*)d_in[7];
  const float* lk2  = (const float*)d_in[8];
  const float* ln_g = (const float*)d_in[9];
  const float* ln_b = (const float*)d_in[10];
  float* out = (float*)d_out;

  const size_t MN = (size_t)B_ * N_ * E_; // 4194304
  ushort* xb    = (ushort*)d_ws;          // bf16 x              (8 MB)
  ushort* wqkvt = xb + MN;                // bf16 [Wq;Wk;Wv]^T   (6 MB)
  ushort* wot   = wqkvt + 3 * 1048576;    // bf16 Wo^T           (2 MB)
  ushort* qkb   = wot + 1048576;          // bf16 qk [4096][2048] (16 MB)
  ushort* vtb   = qkb + (size_t)4096 * 2048; // bf16 v^T [1024][4096] (8 MB)
  float*  lam   = (float*)(vtb + MN);
  ushort* onorm = xb;                     // reuse x buffer after the projection gemm

  prep_kernel<<<dim3(3073), 256, 0, stream>>>(x, Wq, Wk, Wv, Wo, lq1, lk1, lq2, lk2,
                                              xb, wqkvt, wot, lam);

  // fused QK + V^T projection, 256^2 tiles, single-barrier dbuf (192 blocks, XCD-chunked)
  gemm_qkv<<<dim3(192), 512, 0, stream>>>(xb, wqkvt, qkb, vtb, 0.125f * LOG2E);

  // paired-half-head flash with fused combine+LN (256 blocks = 1/CU), 2-tile barrier phases
  flash_kernel<<<dim3(256), 512, 0, stream>>>(qkb, vtb, lam, ln_g, ln_b, onorm);

  // output projection, 2-tile phases + XCD chunk (512 blocks = 2/CU)
  gemm_out<<<dim3(512), 256, 0, stream>>>(onorm, wot, out);
}